// Round 4
// baseline (39.079 us; speedup 1.0000x reference)
//
#include <hip/hip_runtime.h>

typedef __attribute__((ext_vector_type(4))) float f32x4;
typedef __attribute__((ext_vector_type(8))) short bf16x8;
typedef _Float16 f16x8 __attribute__((ext_vector_type(8)));

#define MFMA16(a, b, c) __builtin_amdgcn_mfma_f32_16x16x32_f16((a), (b), (c), 0, 0, 0)
#define MFMABF(a, b, c) __builtin_amdgcn_mfma_f32_16x16x32_bf16((a), (b), (c), 0, 0, 0)

constexpr size_t TILE_FRAG_BYTES = 8192;               // 64x64 fp16, frag-major
constexpr size_t NTILES = 512;                         // B*H*16
constexpr size_t ARR_S  = NTILES * TILE_FRAG_BYTES;    // 4 MiB (K or V array)
constexpr size_t WS_NEED = 2 * ARR_S;                  // Kfrag + Vfrag

// Swizzled byte offset inside a 64-row x 64-col 2-byte-elem LDS tile/strip.
__device__ __forceinline__ int swz_off(int row, int col) {
    return (row * 128 + col * 2) ^ ((row & 7) << 4);
}
__device__ __forceinline__ f16x8 ld_frag16(const char* tile, int row, int col) {
    return *(const f16x8*)(tile + swz_off(row, col));
}

// ---------------------------------------------------------------------------
// Pre-pass: K -> fp16 fragment-major tiles (direct, no LDS); V -> transposed
// fp16 fragment-major tiles (LDS transpose). Frag f=(j*2+kk), lane=g*16+l16:
//   K-frag elem e = K[j*16+l16][kk*32+g*8+e]      (B-frag for QK^T)
//   V-frag elem e = V[kk*32+g*8+e][j*16+l16]      (B-frag for PV, V^T)
// A wave's fragment load in the main kernel is 1 KiB contiguous.
// ---------------------------------------------------------------------------
__global__ __launch_bounds__(256) void bigbird_prepass(
    const float* __restrict__ K, const float* __restrict__ V,
    char* __restrict__ ws) {
    __shared__ float vf[64][66];
    const int tile = blockIdx.x;
    const int tid  = threadIdx.x;
    const float* Kt = K + (size_t)tile * 4096;
    const float* Vt = V + (size_t)tile * 4096;
    f16x8* Ko = (f16x8*)(ws + (size_t)tile * TILE_FRAG_BYTES);
    f16x8* Vo = (f16x8*)(ws + ARR_S + (size_t)tile * TILE_FRAG_BYTES);

    {   // V: coalesced load into padded LDS (for transposed gather below)
        const int row = tid >> 2;
        const int c0  = (tid & 3) << 4;
        const float* p = Vt + row * 64 + c0;
        f32x4 e0 = *(const f32x4*)p,       e1 = *(const f32x4*)(p + 4),
              e2 = *(const f32x4*)(p + 8), e3 = *(const f32x4*)(p + 12);
#pragma unroll
        for (int e = 0; e < 4; ++e) {
            vf[row][c0 + e] = e0[e];     vf[row][c0 + 4 + e] = e1[e];
            vf[row][c0 + 8 + e] = e2[e]; vf[row][c0 + 12 + e] = e3[e];
        }
    }
    // K: direct global->convert->frag store (no LDS round trip).
#pragma unroll
    for (int t = 0; t < 2; ++t) {
        int s = tid + t * 256;              // chunk 0..511
        int f = s >> 6, lane = s & 63;
        int j = f >> 1, kk = f & 1;
        int l16 = lane & 15, g = lane >> 4;
        const float* p = Kt + (j * 16 + l16) * 64 + kk * 32 + g * 8;
        f32x4 a = *(const f32x4*)p;
        f32x4 c = *(const f32x4*)(p + 4);
        f16x8 kv;
#pragma unroll
        for (int e = 0; e < 4; ++e) {
            kv[e]     = (_Float16)a[e];
            kv[4 + e] = (_Float16)c[e];
        }
        Ko[s] = kv;
    }
    __syncthreads();
    // V frag from transposed LDS gather.
#pragma unroll
    for (int t = 0; t < 2; ++t) {
        int s = tid + t * 256;
        int f = s >> 6, lane = s & 63;
        int j = f >> 1, kk = f & 1;
        int l16 = lane & 15, g = lane >> 4;
        f16x8 vv;
#pragma unroll
        for (int e = 0; e < 8; ++e)
            vv[e] = (_Float16)vf[kk * 32 + g * 8 + e][j * 16 + l16];
        Vo[s] = vv;
    }
}

// ---------------------------------------------------------------------------
// Main: one WG per (b,h,32-row sub-block); 4 waves = (row-strip ws x
// tb-subset wt). Waves free-run over their tb subset; 2-way combine at end.
// ---------------------------------------------------------------------------
__global__ __launch_bounds__(256, 4) void bigbird_main(
    const float* __restrict__ Q, const float* __restrict__ M,
    const char* __restrict__ ws, float* __restrict__ Out) {
    constexpr int H = 16, F = 1024, D = 64;

    __shared__ char  p_sm[4][2048];     // per-wave 16-row P strip
    __shared__ float O_sm[32][65];      // combine buffer (padded)
    __shared__ float m_sm[2][32], l_sm[2][32];
    __shared__ int flags[16];
    __shared__ int list[16];
    __shared__ int ncnt;

    // XCD-grouped remap: 32 sub-blocks of one (b,h) on one XCD.
    const int i0  = blockIdx.x;         // 0..1023
    const int xcd = i0 & 7;
    const int q0  = i0 >> 3;            // 0..127
    const int grp = xcd * 4 + (q0 >> 5);// 0..31 == b*16+h
    const int sb  = q0 & 31;            // 32-row sub-block
    const int b   = grp >> 4;
    const int h   = grp & 15;
    const int bh  = grp;

    const int tid  = threadIdx.x;
    const int lane = tid & 63;
    const int w    = tid >> 6;          // 0..3
    const int ws_  = w & 1;             // row strip (16 rows)
    const int wt   = w >> 1;            // tb subset
    const int g    = lane >> 4;
    const int l16  = lane & 15;

    if (tid < 16)
        flags[tid] = (M[((size_t)(h * 1024 + sb * 32)) * 1024 + tid * 64] > 0.5f) ? 1 : 0;

    // Q A-fragments (fp16, x0.125) straight from global.
    f16x8 qf[2];
    {
        const float* qr = Q + ((size_t)bh * F + sb * 32 + ws_ * 16 + l16) * D;
#pragma unroll
        for (int kk = 0; kk < 2; ++kk) {
            const float* p = qr + kk * 32 + g * 8;
            f32x4 a = *(const f32x4*)p;
            f32x4 c = *(const f32x4*)(p + 4);
#pragma unroll
            for (int e = 0; e < 8; ++e)
                qf[kk][e] = (_Float16)((e < 4 ? a[e] : c[e - 4]) * 0.125f);
        }
    }
    __syncthreads();
    if (tid == 0) {
        int nn = 0;
        for (int t = 0; t < 16; ++t)
            if (flags[t]) list[nn++] = t;
        ncnt = nn;
    }
    __syncthreads();
    const int n = ncnt;

    f32x4 acc[4];
    float m_r[4], l_r[4];
#pragma unroll
    for (int j = 0; j < 4; ++j) acc[j] = f32x4{0.f, 0.f, 0.f, 0.f};
#pragma unroll
    for (int r = 0; r < 4; ++r) { m_r[r] = -1e30f; l_r[r] = 0.f; }

    const f16x8* Kbase = (const f16x8*)ws + (size_t)bh * 16 * 512;
    const f16x8* Vbase = (const f16x8*)(ws + ARR_S) + (size_t)bh * 16 * 512;
    char* pw = p_sm[w];

    for (int i = wt; i < n; i += 2) {
        const int tb = list[i];
        const f16x8* Kf = Kbase + (size_t)tb * 512;
        const f16x8* Vf = Vbase + (size_t)tb * 512;

        f16x8 kfr[4][2], vfr[4][2];
#pragma unroll
        for (int j = 0; j < 4; ++j)
#pragma unroll
            for (int kk = 0; kk < 2; ++kk) {
                kfr[j][kk] = Kf[(j * 2 + kk) * 64 + lane];
                vfr[j][kk] = Vf[(j * 2 + kk) * 64 + lane];
            }

        // S = Q K^T
        f32x4 s[4];
#pragma unroll
        for (int j = 0; j < 4; ++j) {
            s[j] = f32x4{0.f, 0.f, 0.f, 0.f};
#pragma unroll
            for (int kk = 0; kk < 2; ++kk)
                s[j] = MFMA16(qf[kk], kfr[j][kk], s[j]);
        }

        // Online softmax (rows g*4+r within strip, col j*16+l16).
        float rmax[4];
#pragma unroll
        for (int r = 0; r < 4; ++r)
            rmax[r] = fmaxf(fmaxf(s[0][r], s[1][r]), fmaxf(s[2][r], s[3][r]));
#pragma unroll
        for (int off = 1; off < 16; off <<= 1)
#pragma unroll
            for (int r = 0; r < 4; ++r)
                rmax[r] = fmaxf(rmax[r], __shfl_xor(rmax[r], off, 64));
        float alpha[4], psum[4];
#pragma unroll
        for (int r = 0; r < 4; ++r) {
            float mn = fmaxf(m_r[r], rmax[r]);
            alpha[r] = __expf(m_r[r] - mn);
            m_r[r]   = mn;
            psum[r]  = 0.f;
        }
#pragma unroll
        for (int j = 0; j < 4; ++j)
#pragma unroll
            for (int r = 0; r < 4; ++r) {
                float pe = __expf(s[j][r] - m_r[r]);
                s[j][r] = pe;
                psum[r] += pe;
            }
#pragma unroll
        for (int off = 1; off < 16; off <<= 1)
#pragma unroll
            for (int r = 0; r < 4; ++r)
                psum[r] += __shfl_xor(psum[r], off, 64);
#pragma unroll
        for (int r = 0; r < 4; ++r)
            l_r[r] = l_r[r] * alpha[r] + psum[r];
#pragma unroll
        for (int j = 0; j < 4; ++j)
#pragma unroll
            for (int r = 0; r < 4; ++r)
                acc[j][r] *= alpha[r];

        // P (fp16) -> wave-private LDS strip: C-layout -> A-frag reshape.
#pragma unroll
        for (int j = 0; j < 4; ++j)
#pragma unroll
            for (int r = 0; r < 4; ++r)
                *(_Float16*)(pw + swz_off(g * 4 + r, j * 16 + l16)) = (_Float16)s[j][r];
        asm volatile("s_waitcnt lgkmcnt(0)" ::: "memory");
        __builtin_amdgcn_sched_barrier(0);

        // O += P * V
#pragma unroll
        for (int kk = 0; kk < 2; ++kk) {
            f16x8 pa = ld_frag16(pw, l16, kk * 32 + g * 8);
#pragma unroll
            for (int jd = 0; jd < 4; ++jd)
                acc[jd] = MFMA16(pa, vfr[jd][kk], acc[jd]);
        }
    }

    // ---- 2-way combine across wt ----
    if (l16 == 0) {
#pragma unroll
        for (int r = 0; r < 4; ++r) {
            int row = ws_ * 16 + g * 4 + r;
            m_sm[wt][row] = m_r[r];
            l_sm[wt][row] = l_r[r];
        }
    }
    __syncthreads();
    float inv_l[4];
#pragma unroll
    for (int r = 0; r < 4; ++r) {
        int row = ws_ * 16 + g * 4 + r;
        float m0 = m_sm[0][row], m1 = m_sm[1][row];
        float mm = fmaxf(m0, m1);
        float ll = l_sm[0][row] * __expf(m0 - mm) + l_sm[1][row] * __expf(m1 - mm);
        inv_l[r] = 1.0f / ll;
        float sc = __expf(m_r[r] - mm);
#pragma unroll
        for (int j = 0; j < 4; ++j) acc[j][r] *= sc;
    }
    if (wt == 0) {
#pragma unroll
        for (int j = 0; j < 4; ++j)
#pragma unroll
            for (int r = 0; r < 4; ++r)
                O_sm[ws_ * 16 + g * 4 + r][j * 16 + l16] = acc[j][r];
    }
    __syncthreads();
    if (wt == 1) {
#pragma unroll
        for (int j = 0; j < 4; ++j)
#pragma unroll
            for (int r = 0; r < 4; ++r)
                O_sm[ws_ * 16 + g * 4 + r][j * 16 + l16] += acc[j][r];
    }
    __syncthreads();

    // Epilogue: wave (ws_,wt) writes its rows, cols wt*32..wt*32+31.
#pragma unroll
    for (int r = 0; r < 4; ++r) {
        int row = ws_ * 16 + g * 4 + r;
        int f = sb * 32 + row;
        float inv = inv_l[r];
        float* ob = Out + ((size_t)(b * F + f) * H + h) * D;
#pragma unroll
        for (int j2 = 0; j2 < 2; ++j2) {
            int col = wt * 32 + j2 * 16 + l16;
            ob[col] = O_sm[row][col] * inv;
        }
    }
}

// ---------------------------------------------------------------------------
// Fallback (verified R0-style kernel): used only if ws is too small.
// ---------------------------------------------------------------------------
__device__ __forceinline__ unsigned short f2bf(float x) {
    unsigned u = __builtin_bit_cast(unsigned, x);
    unsigned r = u + 0x7fffu + ((u >> 16) & 1u);
    return (unsigned short)(r >> 16);
}
__device__ __forceinline__ float bf2f(unsigned short h) {
    return __builtin_bit_cast(float, (unsigned)h << 16);
}
__device__ __forceinline__ bf16x8 ld_fragb(const char* tile, int row, int col) {
    return *(const bf16x8*)(tile + swz_off(row, col));
}
__device__ __forceinline__ void stage_rm_fb(const float* __restrict__ src,
                                            char* hi_t, char* lo_t, float scale) {
    const int tid = threadIdx.x;
    const int row = tid >> 2;
    const int c0  = (tid & 3) << 4;
    const float* p = src + row * 64 + c0;
    f32x4 vv[4] = { *(const f32x4*)(p), *(const f32x4*)(p + 4),
                    *(const f32x4*)(p + 8), *(const f32x4*)(p + 12) };
    bf16x8 h2[2], l2[2];
#pragma unroll
    for (int e = 0; e < 16; ++e) {
        float x = vv[e >> 2][e & 3] * scale;
        unsigned short hb = f2bf(x);
        unsigned short lb = f2bf(x - bf2f(hb));
        h2[e >> 3][e & 7] = (short)hb;
        l2[e >> 3][e & 7] = (short)lb;
    }
#pragma unroll
    for (int gi = 0; gi < 2; ++gi) {
        int off = swz_off(row, c0 + gi * 8);
        *(bf16x8*)(hi_t + off) = h2[gi];
        *(bf16x8*)(lo_t + off) = l2[gi];
    }
}
__device__ __forceinline__ void stage_tr_fb(const float* __restrict__ src,
                                            char* hi_t, char* lo_t) {
    const int tid = threadIdx.x;
    const int t  = tid >> 2;
    const int c0 = (tid & 3) << 4;
    const float* p = src + t * 64 + c0;
    f32x4 vv[4] = { *(const f32x4*)(p), *(const f32x4*)(p + 4),
                    *(const f32x4*)(p + 8), *(const f32x4*)(p + 12) };
#pragma unroll
    for (int e = 0; e < 16; ++e) {
        float x = vv[e >> 2][e & 3];
        unsigned short hb = f2bf(x);
        unsigned short lb = f2bf(x - bf2f(hb));
        int d = c0 + e;
        int off = (d * 128 + t * 2) ^ ((d & 7) << 4);
        *(unsigned short*)(hi_t + off) = hb;
        *(unsigned short*)(lo_t + off) = lb;
    }
}
__global__ __launch_bounds__(256) void bigbird_kernel_fb(
    const float* __restrict__ Q, const float* __restrict__ K,
    const float* __restrict__ V, const float* __restrict__ M,
    float* __restrict__ Out) {
    constexpr int H = 16, F = 1024, D = 64;
    __shared__ char kq_hi[8192];
    __shared__ char kq_lo[8192];
    __shared__ char vt_hi[8192];
    __shared__ char vt_lo[8192];
    __shared__ char p_smf[8192];
    __shared__ int flags[16];
    const int bid = blockIdx.x;
    const int fb  = bid & 15;
    const int h   = (bid >> 4) & 15;
    const int b   = bid >> 8;
    const int tid  = threadIdx.x;
    const int lane = tid & 63;
    const int w    = tid >> 6;
    const int g    = lane >> 4;
    const int l16  = lane & 15;
    if (tid < 16)
        flags[tid] = (M[(h * 1024 + fb * 64) * 1024 + tid * 64] > 0.5f) ? 1 : 0;
    const float* qb = Q + ((size_t)(b * H + h) * F + fb * 64) * D;
    stage_rm_fb(qb, kq_hi, kq_lo, 0.125f);
    __syncthreads();
    bf16x8 qh[2], ql[2];
#pragma unroll
    for (int kk = 0; kk < 2; ++kk) {
        qh[kk] = ld_fragb(kq_hi, w * 16 + l16, kk * 32 + g * 8);
        ql[kk] = ld_fragb(kq_lo, w * 16 + l16, kk * 32 + g * 8);
    }
    f32x4 acc[4];
    float m_r[4], l_r[4];
#pragma unroll
    for (int j = 0; j < 4; ++j) acc[j] = f32x4{0.f, 0.f, 0.f, 0.f};
#pragma unroll
    for (int r = 0; r < 4; ++r) { m_r[r] = -1e30f; l_r[r] = 0.f; }
    const float* kb = K + (size_t)(b * H + h) * 1024 * D;
    const float* vb = V + (size_t)(b * H + h) * 1024 * D;
    for (int tb = 0; tb < 16; ++tb) {
        if (!flags[tb]) continue;
        __syncthreads();
        stage_rm_fb(kb + tb * 64 * D, kq_hi, kq_lo, 1.0f);
        stage_tr_fb(vb + tb * 64 * D, vt_hi, vt_lo);
        __syncthreads();
        f32x4 s[4];
#pragma unroll
        for (int j = 0; j < 4; ++j) {
            s[j] = f32x4{0.f, 0.f, 0.f, 0.f};
#pragma unroll
            for (int kk = 0; kk < 2; ++kk) {
                bf16x8 bhf = ld_fragb(kq_hi, j * 16 + l16, kk * 32 + g * 8);
                bf16x8 blf = ld_fragb(kq_lo, j * 16 + l16, kk * 32 + g * 8);
                s[j] = MFMABF(qh[kk], bhf, s[j]);
                s[j] = MFMABF(qh[kk], blf, s[j]);
                s[j] = MFMABF(ql[kk], bhf, s[j]);
            }
        }
        float rmax[4];
#pragma unroll
        for (int r = 0; r < 4; ++r)
            rmax[r] = fmaxf(fmaxf(s[0][r], s[1][r]), fmaxf(s[2][r], s[3][r]));
#pragma unroll
        for (int off = 1; off < 16; off <<= 1)
#pragma unroll
            for (int r = 0; r < 4; ++r)
                rmax[r] = fmaxf(rmax[r], __shfl_xor(rmax[r], off, 64));
        float alpha[4], psum[4];
#pragma unroll
        for (int r = 0; r < 4; ++r) {
            float mn = fmaxf(m_r[r], rmax[r]);
            alpha[r] = __expf(m_r[r] - mn);
            m_r[r]   = mn;
            psum[r]  = 0.f;
        }
#pragma unroll
        for (int j = 0; j < 4; ++j)
#pragma unroll
            for (int r = 0; r < 4; ++r) {
                float pe = __expf(s[j][r] - m_r[r]);
                s[j][r] = pe;
                psum[r] += pe;
            }
#pragma unroll
        for (int off = 1; off < 16; off <<= 1)
#pragma unroll
            for (int r = 0; r < 4; ++r)
                psum[r] += __shfl_xor(psum[r], off, 64);
#pragma unroll
        for (int r = 0; r < 4; ++r)
            l_r[r] = l_r[r] * alpha[r] + psum[r];
#pragma unroll
        for (int j = 0; j < 4; ++j)
#pragma unroll
            for (int r = 0; r < 4; ++r)
                acc[j][r] *= alpha[r];
#pragma unroll
        for (int j = 0; j < 4; ++j)
#pragma unroll
            for (int r = 0; r < 4; ++r) {
                int row = w * 16 + g * 4 + r;
                *(unsigned short*)(p_smf + swz_off(row, j * 16 + l16)) = f2bf(s[j][r]);
            }
        __syncthreads();
#pragma unroll
        for (int kk = 0; kk < 2; ++kk) {
            bf16x8 pa = ld_fragb(p_smf, w * 16 + l16, kk * 32 + g * 8);
#pragma unroll
            for (int jd = 0; jd < 4; ++jd) {
                bf16x8 vh = ld_fragb(vt_hi, jd * 16 + l16, kk * 32 + g * 8);
                bf16x8 vl = ld_fragb(vt_lo, jd * 16 + l16, kk * 32 + g * 8);
                acc[jd] = MFMABF(pa, vh, acc[jd]);
                acc[jd] = MFMABF(pa, vl, acc[jd]);
            }
        }
    }
#pragma unroll
    for (int r = 0; r < 4; ++r) {
        float inv = 1.0f / l_r[r];
        int f = fb * 64 + w * 16 + g * 4 + r;
        float* ob = Out + ((size_t)(b * F + f) * H + h) * D;
#pragma unroll
        for (int jd = 0; jd < 4; ++jd)
            ob[jd * 16 + l16] = acc[jd][r] * inv;
    }
}

extern "C" void kernel_launch(void* const* d_in, const int* in_sizes, int n_in,
                              void* d_out, int out_size, void* d_ws, size_t ws_size,
                              hipStream_t stream) {
    const float* q = (const float*)d_in[0];
    const float* k = (const float*)d_in[1];
    const float* v = (const float*)d_in[2];
    const float* m = (const float*)d_in[3];
    float* out = (float*)d_out;
    if (ws_size >= WS_NEED) {
        bigbird_prepass<<<dim3(512), dim3(256), 0, stream>>>(k, v, (char*)d_ws);
        bigbird_main<<<dim3(1024), dim3(256), 0, stream>>>(q, m, (const char*)d_ws, out);
    } else {
        bigbird_kernel_fb<<<dim3(512), dim3(256), 0, stream>>>(q, k, v, m, out);
    }
}